// Round 1
// baseline (457.803 us; speedup 1.0000x reference)
//
#include <hip/hip_runtime.h>
#include <hip/hip_bf16.h>

// GraphSAGE 3-layer, N=50000, d=64, E=800000, fp32.
// Plan: build CSR once (hist -> scan -> scatter), then per layer:
//   agg: wave-per-node mean aggregation (pull, no atomics)
//   gemm: out = mean@Wl + h@Wr + b (+ReLU), fp32 vector ALU, LDS-tiled.

#define D 64

__global__ __launch_bounds__(256)
void zero_kernel(int* __restrict__ p, int n) {
    int i = blockIdx.x * blockDim.x + threadIdx.x;
    if (i < n) p[i] = 0;
}

__global__ __launch_bounds__(256)
void hist_kernel(const int* __restrict__ dst, int* __restrict__ deg,
                 int n_edges, int n_nodes) {
    int e = blockIdx.x * blockDim.x + threadIdx.x;
    if (e < n_edges) {
        int d = dst[e];
        if ((unsigned)d < (unsigned)n_nodes) atomicAdd(&deg[d], 1);
    }
}

// Single-block exclusive scan over deg -> offsets (and cursor copy).
__global__ __launch_bounds__(1024)
void scan_kernel(const int* __restrict__ deg, int* __restrict__ offsets,
                 int* __restrict__ cursor, int n_nodes) {
    __shared__ int sums[1024];
    const int T = 1024;
    int tid = threadIdx.x;
    int chunk = (n_nodes + T - 1) / T;
    int start = tid * chunk;
    int end = min(start + chunk, n_nodes);
    int s = 0;
    for (int i = start; i < end; i++) s += deg[i];
    sums[tid] = s;
    __syncthreads();
    // Hillis-Steele inclusive scan in LDS
    for (int off = 1; off < T; off <<= 1) {
        int v = 0;
        if (tid >= off) v = sums[tid - off];
        __syncthreads();
        if (tid >= off) sums[tid] += v;
        __syncthreads();
    }
    int base = (tid > 0) ? sums[tid - 1] : 0;
    for (int i = start; i < end; i++) {
        offsets[i] = base;
        cursor[i] = base;
        base += deg[i];
    }
    if (tid == 0) offsets[n_nodes] = sums[T - 1];
}

__global__ __launch_bounds__(256)
void scatter_kernel(const int* __restrict__ src, const int* __restrict__ dst,
                    int* __restrict__ cursor, int* __restrict__ csr,
                    int n_edges, int n_nodes) {
    int e = blockIdx.x * blockDim.x + threadIdx.x;
    if (e < n_edges) {
        int d = dst[e];
        if ((unsigned)d < (unsigned)n_nodes) {
            int s = src[e];
            if ((unsigned)s >= (unsigned)n_nodes) s = 0;
            int p = atomicAdd(&cursor[d], 1);
            csr[p] = s;
        }
    }
}

// One wave per node; lane = feature. Mean of neighbor rows.
__global__ __launch_bounds__(256)
void agg_kernel(const float* __restrict__ h, const int* __restrict__ offsets,
                const int* __restrict__ csr, float* __restrict__ mean,
                int n_nodes) {
    int wid = (int)((blockIdx.x * (unsigned)blockDim.x + threadIdx.x) >> 6);
    int lane = threadIdx.x & 63;
    if (wid >= n_nodes) return;
    int beg = offsets[wid];
    int end = offsets[wid + 1];
    float acc = 0.0f;
    int i = beg;
    for (; i + 4 <= end; i += 4) {
        int s0 = csr[i], s1 = csr[i + 1], s2 = csr[i + 2], s3 = csr[i + 3];
        float v0 = h[s0 * D + lane];
        float v1 = h[s1 * D + lane];
        float v2 = h[s2 * D + lane];
        float v3 = h[s3 * D + lane];
        acc += v0 + v1 + v2 + v3;
    }
    for (; i < end; i++) acc += h[csr[i] * D + lane];
    float c = (float)max(end - beg, 1);
    mean[wid * D + lane] = acc / c;
}

// out[n][j] = sum_k mean[n][k]*Wl[k][j] + h[n][k]*Wr[k][j] + b[j], optional ReLU.
// Block: 256 threads, 64-node tile. Thread computes 8 nodes x 2 features.
#define M_TILE 64

__global__ __launch_bounds__(256)
void gemm_kernel(const float* __restrict__ mean, const float* __restrict__ h,
                 const float* __restrict__ Wl, const float* __restrict__ Wr,
                 const float* __restrict__ bias, float* __restrict__ out,
                 int relu, int n_nodes) {
    __shared__ float sWl[D * D];
    __shared__ float sWr[D * D];
    __shared__ float sAm[M_TILE * D];
    __shared__ float sAh[M_TILE * D];

    const int t = threadIdx.x;
    const int n0 = blockIdx.x * M_TILE;

    // Stage weights: 4096 floats each = 1024 float4
    {
        const float4* wl4 = (const float4*)Wl;
        const float4* wr4 = (const float4*)Wr;
        float4* sWl4 = (float4*)sWl;
        float4* sWr4 = (float4*)sWr;
        for (int i = t; i < 1024; i += 256) {
            sWl4[i] = wl4[i];
            sWr4[i] = wr4[i];
        }
    }
    // Stage A tiles: 64 rows x 64 cols = 1024 float4 each
    {
        float4* sAm4 = (float4*)sAm;
        float4* sAh4 = (float4*)sAh;
        const float4* m4 = (const float4*)mean;
        const float4* h4 = (const float4*)h;
        for (int i = t; i < M_TILE * (D / 4); i += 256) {
            int row = i / (D / 4);
            int col = i % (D / 4);
            int node = n0 + row;
            if (node < n_nodes) {
                sAm4[i] = m4[node * (D / 4) + col];
                sAh4[i] = h4[node * (D / 4) + col];
            } else {
                sAm4[i] = make_float4(0.f, 0.f, 0.f, 0.f);
                sAh4[i] = make_float4(0.f, 0.f, 0.f, 0.f);
            }
        }
    }
    __syncthreads();

    const int jp = (t & 31) * 2;  // feature pair base
    const int nb = (t >> 5) * 8;  // node base within tile (8 groups of 8)

    float acc0[8], acc1[8];
#pragma unroll
    for (int i = 0; i < 8; i++) { acc0[i] = 0.f; acc1[i] = 0.f; }

    for (int k = 0; k < D; k += 4) {
        float2 wl[4], wr[4];
#pragma unroll
        for (int kk = 0; kk < 4; kk++) {
            wl[kk] = *(const float2*)&sWl[(k + kk) * D + jp];
            wr[kk] = *(const float2*)&sWr[(k + kk) * D + jp];
        }
#pragma unroll
        for (int i = 0; i < 8; i++) {
            float4 m4 = *(const float4*)&sAm[(nb + i) * D + k];
            float4 h4 = *(const float4*)&sAh[(nb + i) * D + k];
            acc0[i] += m4.x * wl[0].x + h4.x * wr[0].x;
            acc0[i] += m4.y * wl[1].x + h4.y * wr[1].x;
            acc0[i] += m4.z * wl[2].x + h4.z * wr[2].x;
            acc0[i] += m4.w * wl[3].x + h4.w * wr[3].x;
            acc1[i] += m4.x * wl[0].y + h4.x * wr[0].y;
            acc1[i] += m4.y * wl[1].y + h4.y * wr[1].y;
            acc1[i] += m4.z * wl[2].y + h4.z * wr[2].y;
            acc1[i] += m4.w * wl[3].y + h4.w * wr[3].y;
        }
    }

    float b0 = bias[jp];
    float b1 = bias[jp + 1];
#pragma unroll
    for (int i = 0; i < 8; i++) {
        int node = n0 + nb + i;
        if (node < n_nodes) {
            float v0 = acc0[i] + b0;
            float v1 = acc1[i] + b1;
            if (relu) { v0 = fmaxf(v0, 0.f); v1 = fmaxf(v1, 0.f); }
            *(float2*)&out[node * D + jp] = make_float2(v0, v1);
        }
    }
}

extern "C" void kernel_launch(void* const* d_in, const int* in_sizes, int n_in,
                              void* d_out, int out_size, void* d_ws, size_t ws_size,
                              hipStream_t stream) {
    const float* x  = (const float*)d_in[0];
    const int*   ei = (const int*)d_in[1];
    const int n_nodes = in_sizes[0] / D;     // 50000
    const int n_edges = in_sizes[1] / 2;     // 800000
    const int* src = ei;
    const int* dst = ei + n_edges;

    const float* Wl1 = (const float*)d_in[2];
    const float* Wr1 = (const float*)d_in[3];
    const float* b1  = (const float*)d_in[4];
    const float* Wl2 = (const float*)d_in[5];
    const float* Wr2 = (const float*)d_in[6];
    const float* b2  = (const float*)d_in[7];
    const float* Wl3 = (const float*)d_in[8];
    const float* Wr3 = (const float*)d_in[9];
    const float* b3  = (const float*)d_in[10];

    // Workspace carve-up (256B aligned)
    char* w = (char*)d_ws;
    auto alloc = [&](size_t bytes) -> char* {
        char* p = w;
        w += (bytes + 255) & ~(size_t)255;
        return p;
    };
    int*   deg     = (int*)alloc((size_t)n_nodes * 4);
    int*   offsets = (int*)alloc(((size_t)n_nodes + 1) * 4);
    int*   cursor  = (int*)alloc((size_t)n_nodes * 4);
    int*   csr     = (int*)alloc((size_t)n_edges * 4);
    float* mean    = (float*)alloc((size_t)n_nodes * D * 4);
    float* h1      = (float*)alloc((size_t)n_nodes * D * 4);
    float* h2      = (float*)d_out;  // safe: layer-3 gemm reads only its own tile rows before writing them

    const int eb = (n_edges + 255) / 256;
    const int nbk = (n_nodes + 255) / 256;
    const int agg_blocks  = (n_nodes + 3) / 4;           // 4 waves/block, wave per node
    const int gemm_blocks = (n_nodes + M_TILE - 1) / M_TILE;

    // CSR build
    zero_kernel<<<nbk, 256, 0, stream>>>(deg, n_nodes);
    hist_kernel<<<eb, 256, 0, stream>>>(dst, deg, n_edges, n_nodes);
    scan_kernel<<<1, 1024, 0, stream>>>(deg, offsets, cursor, n_nodes);
    scatter_kernel<<<eb, 256, 0, stream>>>(src, dst, cursor, csr, n_edges, n_nodes);

    // Layer 1: x -> h1 (ReLU)
    agg_kernel<<<agg_blocks, 256, 0, stream>>>(x, offsets, csr, mean, n_nodes);
    gemm_kernel<<<gemm_blocks, 256, 0, stream>>>(mean, x, Wl1, Wr1, b1, h1, 1, n_nodes);

    // Layer 2: h1 -> h2 (ReLU)
    agg_kernel<<<agg_blocks, 256, 0, stream>>>(h1, offsets, csr, mean, n_nodes);
    gemm_kernel<<<gemm_blocks, 256, 0, stream>>>(mean, h1, Wl2, Wr2, b2, h2, 1, n_nodes);

    // Layer 3: h2 -> out (no activation)
    agg_kernel<<<agg_blocks, 256, 0, stream>>>(h2, offsets, csr, mean, n_nodes);
    gemm_kernel<<<gemm_blocks, 256, 0, stream>>>(mean, h2, Wl3, Wr3, b3, (float*)d_out, 0, n_nodes);
}

// Round 2
// 354.776 us; speedup vs baseline: 1.2904x; 1.2904x over previous
//
#include <hip/hip_runtime.h>
#include <hip/hip_bf16.h>

// GraphSAGE 3-layer, N=50000, d=64, E=800000, fp32.
// CSR build (hist -> two-level scan -> scatter), then per layer:
//   agg: wave-per-node mean aggregation (pull, no atomics)
//   gemm: out = mean@Wl + h@Wr + b (+ReLU), fp32 vector ALU, LDS-tiled.
// R2: replaced single-block scan (111 us, 1 CU, latency-serial) with
//     3-kernel two-level scan (partial reduce -> scan partials -> fill).

#define D 64
#define SCAN_B 256

__global__ __launch_bounds__(256)
void zero_kernel(int* __restrict__ p, int n) {
    int i = blockIdx.x * blockDim.x + threadIdx.x;
    if (i < n) p[i] = 0;
}

__global__ __launch_bounds__(256)
void hist_kernel(const int* __restrict__ dst, int* __restrict__ deg,
                 int n_edges, int n_nodes) {
    int e = blockIdx.x * blockDim.x + threadIdx.x;
    if (e < n_edges) {
        int d = dst[e];
        if ((unsigned)d < (unsigned)n_nodes) atomicAdd(&deg[d], 1);
    }
}

// Level 1: per-256-chunk sums.
__global__ __launch_bounds__(SCAN_B)
void partial_kernel(const int* __restrict__ deg, int* __restrict__ partial,
                    int n) {
    __shared__ int s[SCAN_B];
    int t = threadIdx.x;
    int i = blockIdx.x * SCAN_B + t;
    s[t] = (i < n) ? deg[i] : 0;
    __syncthreads();
#pragma unroll
    for (int off = SCAN_B / 2; off > 0; off >>= 1) {
        if (t < off) s[t] += s[t + off];
        __syncthreads();
    }
    if (t == 0) partial[blockIdx.x] = s[0];
}

// Level 2: exclusive scan of the (<=256) partials in one block.
// Also writes offsets[n_nodes] = total.
__global__ __launch_bounds__(SCAN_B)
void scan_partial_kernel(int* __restrict__ partial, int* __restrict__ offsets,
                         int nchunks, int n_nodes) {
    __shared__ int s[SCAN_B];
    int t = threadIdx.x;
    int v = (t < nchunks) ? partial[t] : 0;
    s[t] = v;
    __syncthreads();
#pragma unroll
    for (int off = 1; off < SCAN_B; off <<= 1) {
        int u = 0;
        if (t >= off) u = s[t - off];
        __syncthreads();
        if (t >= off) s[t] += u;
        __syncthreads();
    }
    // exclusive base per chunk
    if (t < nchunks) partial[t] = (t > 0) ? s[t - 1] : 0;
    if (t == 0) offsets[n_nodes] = s[SCAN_B - 1];
}

// Level 3: block-local exclusive scan + chunk base -> offsets & cursor.
__global__ __launch_bounds__(SCAN_B)
void fill_kernel(const int* __restrict__ deg, const int* __restrict__ partial,
                 int* __restrict__ offsets, int* __restrict__ cursor, int n) {
    __shared__ int s[SCAN_B];
    int t = threadIdx.x;
    int i = blockIdx.x * SCAN_B + t;
    int v = (i < n) ? deg[i] : 0;
    s[t] = v;
    __syncthreads();
#pragma unroll
    for (int off = 1; off < SCAN_B; off <<= 1) {
        int u = 0;
        if (t >= off) u = s[t - off];
        __syncthreads();
        if (t >= off) s[t] += u;
        __syncthreads();
    }
    if (i < n) {
        int excl = ((t > 0) ? s[t - 1] : 0) + partial[blockIdx.x];
        offsets[i] = excl;
        cursor[i] = excl;
    }
}

__global__ __launch_bounds__(256)
void scatter_kernel(const int* __restrict__ src, const int* __restrict__ dst,
                    int* __restrict__ cursor, int* __restrict__ csr,
                    int n_edges, int n_nodes) {
    int e = blockIdx.x * blockDim.x + threadIdx.x;
    if (e < n_edges) {
        int d = dst[e];
        if ((unsigned)d < (unsigned)n_nodes) {
            int s = src[e];
            if ((unsigned)s >= (unsigned)n_nodes) s = 0;
            int p = atomicAdd(&cursor[d], 1);
            csr[p] = s;
        }
    }
}

// One wave per node; lane = feature. Mean of neighbor rows.
__global__ __launch_bounds__(256)
void agg_kernel(const float* __restrict__ h, const int* __restrict__ offsets,
                const int* __restrict__ csr, float* __restrict__ mean,
                int n_nodes) {
    int wid = (int)((blockIdx.x * (unsigned)blockDim.x + threadIdx.x) >> 6);
    int lane = threadIdx.x & 63;
    if (wid >= n_nodes) return;
    int beg = offsets[wid];
    int end = offsets[wid + 1];
    float acc = 0.0f;
    int i = beg;
    for (; i + 4 <= end; i += 4) {
        int s0 = csr[i], s1 = csr[i + 1], s2 = csr[i + 2], s3 = csr[i + 3];
        float v0 = h[s0 * D + lane];
        float v1 = h[s1 * D + lane];
        float v2 = h[s2 * D + lane];
        float v3 = h[s3 * D + lane];
        acc += v0 + v1 + v2 + v3;
    }
    for (; i < end; i++) acc += h[csr[i] * D + lane];
    float c = (float)max(end - beg, 1);
    mean[wid * D + lane] = acc / c;
}

// out[n][j] = sum_k mean[n][k]*Wl[k][j] + h[n][k]*Wr[k][j] + b[j], optional ReLU.
// Block: 256 threads, 64-node tile. Thread computes 8 nodes x 2 features.
#define M_TILE 64

__global__ __launch_bounds__(256)
void gemm_kernel(const float* __restrict__ mean, const float* __restrict__ h,
                 const float* __restrict__ Wl, const float* __restrict__ Wr,
                 const float* __restrict__ bias, float* __restrict__ out,
                 int relu, int n_nodes) {
    __shared__ float sWl[D * D];
    __shared__ float sWr[D * D];
    __shared__ float sAm[M_TILE * D];
    __shared__ float sAh[M_TILE * D];

    const int t = threadIdx.x;
    const int n0 = blockIdx.x * M_TILE;

    // Stage weights: 4096 floats each = 1024 float4
    {
        const float4* wl4 = (const float4*)Wl;
        const float4* wr4 = (const float4*)Wr;
        float4* sWl4 = (float4*)sWl;
        float4* sWr4 = (float4*)sWr;
        for (int i = t; i < 1024; i += 256) {
            sWl4[i] = wl4[i];
            sWr4[i] = wr4[i];
        }
    }
    // Stage A tiles: 64 rows x 64 cols = 1024 float4 each
    {
        float4* sAm4 = (float4*)sAm;
        float4* sAh4 = (float4*)sAh;
        const float4* m4 = (const float4*)mean;
        const float4* h4 = (const float4*)h;
        for (int i = t; i < M_TILE * (D / 4); i += 256) {
            int row = i / (D / 4);
            int col = i % (D / 4);
            int node = n0 + row;
            if (node < n_nodes) {
                sAm4[i] = m4[node * (D / 4) + col];
                sAh4[i] = h4[node * (D / 4) + col];
            } else {
                sAm4[i] = make_float4(0.f, 0.f, 0.f, 0.f);
                sAh4[i] = make_float4(0.f, 0.f, 0.f, 0.f);
            }
        }
    }
    __syncthreads();

    const int jp = (t & 31) * 2;  // feature pair base
    const int nb = (t >> 5) * 8;  // node base within tile (8 groups of 8)

    float acc0[8], acc1[8];
#pragma unroll
    for (int i = 0; i < 8; i++) { acc0[i] = 0.f; acc1[i] = 0.f; }

    for (int k = 0; k < D; k += 4) {
        float2 wl[4], wr[4];
#pragma unroll
        for (int kk = 0; kk < 4; kk++) {
            wl[kk] = *(const float2*)&sWl[(k + kk) * D + jp];
            wr[kk] = *(const float2*)&sWr[(k + kk) * D + jp];
        }
#pragma unroll
        for (int i = 0; i < 8; i++) {
            float4 m4 = *(const float4*)&sAm[(nb + i) * D + k];
            float4 h4 = *(const float4*)&sAh[(nb + i) * D + k];
            acc0[i] += m4.x * wl[0].x + h4.x * wr[0].x;
            acc0[i] += m4.y * wl[1].x + h4.y * wr[1].x;
            acc0[i] += m4.z * wl[2].x + h4.z * wr[2].x;
            acc0[i] += m4.w * wl[3].x + h4.w * wr[3].x;
            acc1[i] += m4.x * wl[0].y + h4.x * wr[0].y;
            acc1[i] += m4.y * wl[1].y + h4.y * wr[1].y;
            acc1[i] += m4.z * wl[2].y + h4.z * wr[2].y;
            acc1[i] += m4.w * wl[3].y + h4.w * wr[3].y;
        }
    }

    float b0 = bias[jp];
    float b1 = bias[jp + 1];
#pragma unroll
    for (int i = 0; i < 8; i++) {
        int node = n0 + nb + i;
        if (node < n_nodes) {
            float v0 = acc0[i] + b0;
            float v1 = acc1[i] + b1;
            if (relu) { v0 = fmaxf(v0, 0.f); v1 = fmaxf(v1, 0.f); }
            *(float2*)&out[node * D + jp] = make_float2(v0, v1);
        }
    }
}

extern "C" void kernel_launch(void* const* d_in, const int* in_sizes, int n_in,
                              void* d_out, int out_size, void* d_ws, size_t ws_size,
                              hipStream_t stream) {
    const float* x  = (const float*)d_in[0];
    const int*   ei = (const int*)d_in[1];
    const int n_nodes = in_sizes[0] / D;     // 50000
    const int n_edges = in_sizes[1] / 2;     // 800000
    const int* src = ei;
    const int* dst = ei + n_edges;

    const float* Wl1 = (const float*)d_in[2];
    const float* Wr1 = (const float*)d_in[3];
    const float* b1  = (const float*)d_in[4];
    const float* Wl2 = (const float*)d_in[5];
    const float* Wr2 = (const float*)d_in[6];
    const float* b2  = (const float*)d_in[7];
    const float* Wl3 = (const float*)d_in[8];
    const float* Wr3 = (const float*)d_in[9];
    const float* b3  = (const float*)d_in[10];

    // Workspace carve-up (256B aligned)
    char* w = (char*)d_ws;
    auto alloc = [&](size_t bytes) -> char* {
        char* p = w;
        w += (bytes + 255) & ~(size_t)255;
        return p;
    };
    int*   deg     = (int*)alloc((size_t)n_nodes * 4);
    int*   offsets = (int*)alloc(((size_t)n_nodes + 1) * 4);
    int*   cursor  = (int*)alloc((size_t)n_nodes * 4);
    int*   csr     = (int*)alloc((size_t)n_edges * 4);
    int*   partial = (int*)alloc((size_t)SCAN_B * 4);
    float* mean    = (float*)alloc((size_t)n_nodes * D * 4);
    float* h1      = (float*)alloc((size_t)n_nodes * D * 4);
    float* h2      = (float*)d_out;  // safe: layer-3 gemm reads only its own tile rows before writing them

    const int eb = (n_edges + 255) / 256;
    const int nbk = (n_nodes + 255) / 256;
    const int nchunks = (n_nodes + SCAN_B - 1) / SCAN_B;   // 196 <= 256
    const int agg_blocks  = (n_nodes + 3) / 4;             // 4 waves/block, wave per node
    const int gemm_blocks = (n_nodes + M_TILE - 1) / M_TILE;

    // CSR build
    zero_kernel<<<nbk, 256, 0, stream>>>(deg, n_nodes);
    hist_kernel<<<eb, 256, 0, stream>>>(dst, deg, n_edges, n_nodes);
    partial_kernel<<<nchunks, SCAN_B, 0, stream>>>(deg, partial, n_nodes);
    scan_partial_kernel<<<1, SCAN_B, 0, stream>>>(partial, offsets, nchunks, n_nodes);
    fill_kernel<<<nchunks, SCAN_B, 0, stream>>>(deg, partial, offsets, cursor, n_nodes);
    scatter_kernel<<<eb, 256, 0, stream>>>(src, dst, cursor, csr, n_edges, n_nodes);

    // Layer 1: x -> h1 (ReLU)
    agg_kernel<<<agg_blocks, 256, 0, stream>>>(x, offsets, csr, mean, n_nodes);
    gemm_kernel<<<gemm_blocks, 256, 0, stream>>>(mean, x, Wl1, Wr1, b1, h1, 1, n_nodes);

    // Layer 2: h1 -> h2 (ReLU)
    agg_kernel<<<agg_blocks, 256, 0, stream>>>(h1, offsets, csr, mean, n_nodes);
    gemm_kernel<<<gemm_blocks, 256, 0, stream>>>(mean, h1, Wl2, Wr2, b2, h2, 1, n_nodes);

    // Layer 3: h2 -> out (no activation)
    agg_kernel<<<agg_blocks, 256, 0, stream>>>(h2, offsets, csr, mean, n_nodes);
    gemm_kernel<<<gemm_blocks, 256, 0, stream>>>(mean, h2, Wl3, Wr3, b3, (float*)d_out, 0, n_nodes);
}